// Round 2
// baseline (116.764 us; speedup 1.0000x reference)
//
#include <hip/hip_runtime.h>
#include <hip/hip_cooperative_groups.h>

namespace cg = cooperative_groups;

#define B_ 8
#define N_ 2048
#define F_ 128

// workspace layout (floats)
#define WS_PAJ 0       // [256] per-block partial sums of a_j
#define WS_PS0 256     // [8][32][128] partial S0
#define WS_PS1 33024   // [8][32][128] partial S1

// dynamic LDS carve (floats)
#define L_XT    0        // xT[128*68]  transposed x tile, swizzled
#define L_WL    8704     // wl[128*128] full W (stride 128); aliased as red[8][128] later
#define L_ADJW  25088    // adjw[256]
#define L_PAI   25344    // pai[4][64]
#define L_PAJ   25600    // paj[4][64]
#define L_AJL   25856    // ajL[64]
#define L_AIBL  25920    // aibL[64]  (a_i + adj_b)
#define L_DISB  25984    // disb[64]
#define L_AJD   26048    // ajdL[64]  (a_j * dis)
#define L_PAJS  26112    // pajsum[32]
#define L_S0    26144    // s0[128]
#define L_S1    26272    // s1[128]
#define L_BL    26400    // bl[128]
#define SMEM_FLOATS 26528
#define SMEM_BYTES (SMEM_FLOATS * 4)

__global__ __launch_bounds__(256, 1) void gcn_fused(
    const float* __restrict__ x, const float* __restrict__ adj_w,
    const float* __restrict__ adj_b_p, const float* __restrict__ weight,
    const float* __restrict__ bias, float* __restrict__ outx,
    float* __restrict__ pAj, float* __restrict__ pS0, float* __restrict__ pS1)
{
    extern __shared__ float smem[];
    float* xT   = smem + L_XT;
    float* wl   = smem + L_WL;
    float* adjw = smem + L_ADJW;
    float* pai  = smem + L_PAI;
    float* paj  = smem + L_PAJ;
    float* ajL  = smem + L_AJL;
    float* aibL = smem + L_AIBL;
    float* disb = smem + L_DISB;
    float* ajdL = smem + L_AJD;
    float* pajs = smem + L_PAJS;
    float* s0   = smem + L_S0;
    float* s1   = smem + L_S1;
    float* bl   = smem + L_BL;

    const int bid = blockIdx.x;
    const int b = bid >> 5, mblk = bid & 31;
    const int r0 = mblk * 64;
    const int t = threadIdx.x;
    const int tc = t & 31, tr = t >> 5;

    const float* xblk = x + (size_t)(b * N_ + r0) * F_;

    adjw[t] = adj_w[t];

    // ---- stage x tile transposed+swizzled: (k,row) at xT[k*68 + ((rh^((k>>2)&3))<<3) + rl]
    {
        const int k4 = tc * 4;
        #pragma unroll
        for (int p = 0; p < 8; ++p) {
            const int row = p * 8 + tr;
            const int rh = row >> 3, rl = row & 7;
            const float4 v = *reinterpret_cast<const float4*>(&xblk[row * F_ + k4]);
            const float vv[4] = {v.x, v.y, v.z, v.w};
            #pragma unroll
            for (int i = 0; i < 4; ++i) {
                const int k = k4 + i;
                xT[k * 68 + ((rh ^ ((k >> 2) & 3)) << 3) + rl] = vv[i];
            }
        }
    }
    // ---- stage full W (stride 128: 2-way-free reads, 16-bit ds offsets)
    {
        const int c4 = tc * 4;
        #pragma unroll
        for (int p = 0; p < 16; ++p) {
            const int kk = p * 8 + tr;
            *reinterpret_cast<float4*>(&wl[kk * 128 + c4]) =
                *reinterpret_cast<const float4*>(&weight[kk * F_ + c4]);
        }
    }
    __syncthreads();

    // ---- a_i, a_j per row (k split 4 ways)
    {
        const int row = t & 63, half = t >> 6;
        const int rh = row >> 3, rl = row & 7;
        float ai = 0.f, aj = 0.f;
        for (int k = half * 32; k < half * 32 + 32; ++k) {
            const float v = xT[k * 68 + ((rh ^ ((k >> 2) & 3)) << 3) + rl];
            ai = fmaf(v, adjw[k], ai);
            aj = fmaf(v, adjw[128 + k], aj);
        }
        pai[half * 64 + row] = ai;
        paj[half * 64 + row] = aj;
    }
    __syncthreads();
    if (t < 64) {
        const float ai = pai[t] + pai[64 + t] + pai[128 + t] + pai[192 + t];
        const float aj = paj[t] + paj[64 + t] + paj[128 + t] + paj[192 + t];
        ajL[t] = aj;
        aibL[t] = ai + adj_b_p[0];
        // block partial of sum(a_j): wave-0 reduction over 64 rows
        float s = aj;
        #pragma unroll
        for (int off = 32; off > 0; off >>= 1)
            s += __shfl_down(s, off, 64);
        if (t == 0) pAj[bid] = s;
    }
    __syncthreads();

    // ---- GEMM: rows tr*8..+7, cols {2tc,2tc+1,2tc+64,2tc+65}; W fully resident
    float acc[8][4];
    #pragma unroll
    for (int r = 0; r < 8; ++r)
        #pragma unroll
        for (int j = 0; j < 4; ++j) acc[r][j] = 0.f;

    #pragma unroll 4
    for (int k = 0; k < 128; ++k) {
        const int base = k * 68 + ((tr ^ ((k >> 2) & 3)) << 3);
        const float4 x0 = *reinterpret_cast<const float4*>(&xT[base]);
        const float4 x1 = *reinterpret_cast<const float4*>(&xT[base + 4]);
        const float2 w0 = *reinterpret_cast<const float2*>(&wl[k * 128 + 2 * tc]);
        const float2 w1 = *reinterpret_cast<const float2*>(&wl[k * 128 + 2 * tc + 64]);
        const float xr[8] = {x0.x, x0.y, x0.z, x0.w, x1.x, x1.y, x1.z, x1.w};
        const float wv[4] = {w0.x, w0.y, w1.x, w1.y};
        #pragma unroll
        for (int r = 0; r < 8; ++r)
            #pragma unroll
            for (int j = 0; j < 4; ++j)
                acc[r][j] = fmaf(xr[r], wv[j], acc[r][j]);
    }

    // ---- grid sync #1: all pAj partials visible
    __threadfence();
    cg::this_grid().sync();

    if (t < 32) pajs[t] = pAj[b * 32 + t];
    __syncthreads();
    if (t < 64) {
        float ajs = 0.f;
        #pragma unroll
        for (int i = 0; i < 32; ++i) ajs += pajs[i];
        float deg = 2048.f * aibL[t] + ajs + 1.f;   // 2048*(a_i+b) + sum(a_j) + 1
        deg = fmaxf(deg, 1.f);
        const float d = rsqrtf(deg);
        disb[t] = d;
        ajdL[t] = ajL[t] * d;
    }
    __syncthreads();

    // ---- per-block partial S0/S1 (red aliases wl; W reads all done)
    float ps0[4] = {0.f, 0.f, 0.f, 0.f}, ps1[4] = {0.f, 0.f, 0.f, 0.f};
    #pragma unroll
    for (int r = 0; r < 8; ++r) {
        const int row = tr * 8 + r;
        const float dv = disb[row], av = ajdL[row];
        #pragma unroll
        for (int j = 0; j < 4; ++j) {
            ps0[j] = fmaf(dv, acc[r][j], ps0[j]);
            ps1[j] = fmaf(av, acc[r][j], ps1[j]);
        }
    }
    float* red = wl;
    red[tr * 128 + 2 * tc]      = ps0[0];
    red[tr * 128 + 2 * tc + 1]  = ps0[1];
    red[tr * 128 + 2 * tc + 64] = ps0[2];
    red[tr * 128 + 2 * tc + 65] = ps0[3];
    __syncthreads();
    if (t < 128) {
        float s = 0.f;
        #pragma unroll
        for (int g2 = 0; g2 < 8; ++g2) s += red[g2 * 128 + t];
        pS0[bid * 128 + t] = s;
    }
    __syncthreads();
    red[tr * 128 + 2 * tc]      = ps1[0];
    red[tr * 128 + 2 * tc + 1]  = ps1[1];
    red[tr * 128 + 2 * tc + 64] = ps1[2];
    red[tr * 128 + 2 * tc + 65] = ps1[3];
    __syncthreads();
    if (t < 128) {
        float s = 0.f;
        #pragma unroll
        for (int g2 = 0; g2 < 8; ++g2) s += red[g2 * 128 + t];
        pS1[bid * 128 + t] = s;
    }

    // ---- grid sync #2: all S0/S1 partials visible
    __threadfence();
    cg::this_grid().sync();

    if (t < 128) {
        float s = 0.f;
        for (int kb = 0; kb < 32; ++kb) s += pS0[(b * 32 + kb) * 128 + t];
        s0[t] = s;
        bl[t] = bias[t];
    } else {
        const int c = t - 128;
        float s = 0.f;
        for (int kb = 0; kb < 32; ++kb) s += pS1[(b * 32 + kb) * 128 + c];
        s1[c] = s;
    }
    __syncthreads();

    // ---- epilogue on register accumulators, single out write
    #pragma unroll
    for (int r = 0; r < 8; ++r) {
        const int row = tr * 8 + r;
        const float d = disb[row], ab = aibL[row];
        const int c0 = 2 * tc, c1 = 2 * tc + 64;
        const float v0 = fmaxf(d * (ab * s0[c0]     + s1[c0]     + d * acc[r][0]) + bl[c0],     0.f);
        const float v1 = fmaxf(d * (ab * s0[c0 + 1] + s1[c0 + 1] + d * acc[r][1]) + bl[c0 + 1], 0.f);
        const float v2 = fmaxf(d * (ab * s0[c1]     + s1[c1]     + d * acc[r][2]) + bl[c1],     0.f);
        const float v3 = fmaxf(d * (ab * s0[c1 + 1] + s1[c1 + 1] + d * acc[r][3]) + bl[c1 + 1], 0.f);
        float* op = outx + (size_t)(b * N_ + r0 + row) * F_;
        *reinterpret_cast<float2*>(&op[c0]) = make_float2(v0, v1);
        *reinterpret_cast<float2*>(&op[c1]) = make_float2(v2, v3);
    }
}

extern "C" void kernel_launch(void* const* d_in, const int* in_sizes, int n_in,
                              void* d_out, int out_size, void* d_ws, size_t ws_size,
                              hipStream_t stream) {
    const float* x      = (const float*)d_in[0];
    const float* adj_w  = (const float*)d_in[1];
    const float* adj_b  = (const float*)d_in[2];
    const float* weight = (const float*)d_in[3];
    const float* bias   = (const float*)d_in[4];
    float* out = (float*)d_out;
    float* ws  = (float*)d_ws;

    float* pAj = ws + WS_PAJ;
    float* pS0 = ws + WS_PS0;
    float* pS1 = ws + WS_PS1;

    void* args[] = {(void*)&x, (void*)&adj_w, (void*)&adj_b, (void*)&weight,
                    (void*)&bias, (void*)&out, (void*)&pAj, (void*)&pS0, (void*)&pS1};
    hipLaunchCooperativeKernel((const void*)gcn_fused, dim3(256), dim3(256),
                               args, SMEM_BYTES, stream);
}

// Round 3
// 27.941 us; speedup vs baseline: 4.1789x; 4.1789x over previous
//
#include <hip/hip_runtime.h>

#define N_ 2048
#define F_ 128

// workspace layout (floats)
#define WS_PAJ 0        // [512] per-block partial sums of a_j
#define WS_AIB 512      // [8*2048] a_i + adj_b
#define WS_AJ  16896    // [8*2048] a_j
#define WS_DIS 33280    // [8*2048] dis
#define WS_PT0 49664    // [512][128] partial t0 = sum dis_j * x_j
#define WS_PT1 115200   // [512][128] partial t1 = sum a_j*dis_j * x_j

// ---- K1: per-row a_i,a_j + per-block partial sum(a_j). grid 512 x 256 ----
__global__ __launch_bounds__(256) void k1_arow(
    const float* __restrict__ x, const float* __restrict__ adj_w,
    const float* __restrict__ adj_b_p,
    float* __restrict__ aib, float* __restrict__ aJ, float* __restrict__ pAj)
{
    __shared__ float awl[256];
    __shared__ float sjl[32];
    const int bid = blockIdx.x;
    const int b = bid >> 6, r0 = (bid & 63) * 32;
    const int t = threadIdx.x;
    awl[t] = adj_w[t];
    __syncthreads();
    const int row = t >> 3, kseg = t & 7;
    const float* xp = x + (size_t)(b * N_ + r0 + row) * F_ + kseg * 16;
    float ai = 0.f, aj = 0.f;
    #pragma unroll
    for (int p = 0; p < 4; ++p) {
        const float4 v = *reinterpret_cast<const float4*>(xp + p * 4);
        const float vv[4] = {v.x, v.y, v.z, v.w};
        #pragma unroll
        for (int q = 0; q < 4; ++q) {
            const int k = kseg * 16 + p * 4 + q;
            ai = fmaf(vv[q], awl[k], ai);
            aj = fmaf(vv[q], awl[128 + k], aj);
        }
    }
    #pragma unroll
    for (int m = 1; m < 8; m <<= 1) {
        ai += __shfl_xor(ai, m, 64);
        aj += __shfl_xor(aj, m, 64);
    }
    if (kseg == 0) {
        aib[b * N_ + r0 + row] = ai + adj_b_p[0];
        aJ[b * N_ + r0 + row] = aj;
        sjl[row] = aj;
    }
    __syncthreads();
    if (t < 32) {
        float s = sjl[t];
        #pragma unroll
        for (int off = 16; off > 0; off >>= 1) s += __shfl_down(s, off, 32);
        if (t == 0) pAj[bid] = s;
    }
}

// ---- K2: dis per row + per-block partial t0/t1. grid 512 x 256 ----
__global__ __launch_bounds__(256) void k2_tvec(
    const float* __restrict__ x, const float* __restrict__ pAj,
    const float* __restrict__ aib, const float* __restrict__ aJ,
    float* __restrict__ dis, float* __restrict__ pT0, float* __restrict__ pT1)
{
    __shared__ float al[64];
    __shared__ float disl[32], ajdl[32];
    __shared__ float red[2][128];
    const int bid = blockIdx.x;
    const int b = bid >> 6, r0 = (bid & 63) * 32;
    const int t = threadIdx.x;
    if (t < 64) al[t] = pAj[b * 64 + t];
    __syncthreads();
    if (t < 32) {
        float A = 0.f;
        #pragma unroll
        for (int i = 0; i < 64; ++i) A += al[i];
        const float ab = aib[b * N_ + r0 + t];
        const float deg = fmaxf(2048.f * ab + A + 1.f, 1.f);
        const float d = rsqrtf(deg);
        dis[b * N_ + r0 + t] = d;
        disl[t] = d;
        ajdl[t] = aJ[b * N_ + r0 + t] * d;
    }
    __syncthreads();
    const int c = t & 127, g = t >> 7;
    float s0 = 0.f, s1 = 0.f;
    const float* xp = x + (size_t)(b * N_ + r0 + g * 16) * F_;
    #pragma unroll 4
    for (int r = 0; r < 16; ++r) {
        const float v = xp[r * F_ + c];
        s0 = fmaf(disl[g * 16 + r], v, s0);
        s1 = fmaf(ajdl[g * 16 + r], v, s1);
    }
    red[g][c] = s0;
    __syncthreads();
    if (t < 128) pT0[bid * 128 + t] = red[0][t] + red[1][t];
    __syncthreads();
    red[g][c] = s1;
    __syncthreads();
    if (t < 128) pT1[bid * 128 + t] = red[0][t] + red[1][t];
}

// ---- K3: GEMM + s0/s1 + epilogue, single out write. grid 256 x 256 ----
__global__ __launch_bounds__(256, 1) void k3_gemm(
    const float* __restrict__ x, const float* __restrict__ weight,
    const float* __restrict__ bias, const float* __restrict__ dis,
    const float* __restrict__ aib, const float* __restrict__ pT0,
    const float* __restrict__ pT1, float* __restrict__ outx)
{
    __shared__ float wl[128 * 128];
    __shared__ float t0l[128], t1l[128], s0l[128], s1l[128];
    __shared__ float disl[64], aibl[64], bl[128];

    const int bid = blockIdx.x;
    const int b = bid >> 5, r0 = (bid & 31) * 64;
    const int t = threadIdx.x;
    const int tc = t & 31, tr = t >> 5;
    const int tc4 = tc * 4;

    // stage full W (4096 float4)
    {
        const float4* wg = reinterpret_cast<const float4*>(weight);
        float4* wl4 = reinterpret_cast<float4*>(wl);
        #pragma unroll
        for (int p = 0; p < 16; ++p) wl4[p * 256 + t] = wg[p * 256 + t];
    }
    // reduce t0/t1 partials (64 per batch)
    if (t < 128) {
        float s = 0.f;
        for (int kb = 0; kb < 64; ++kb) s += pT0[(b * 64 + kb) * 128 + t];
        t0l[t] = s;
        bl[t] = bias[t];
    } else {
        const int c = t - 128;
        float s = 0.f;
        for (int kb = 0; kb < 64; ++kb) s += pT1[(b * 64 + kb) * 128 + c];
        t1l[c] = s;
    }
    if (t < 64) {
        disl[t] = dis[b * N_ + r0 + t];
        aibl[t] = aib[b * N_ + r0 + t];
    }
    __syncthreads();

    // GEMM: thread owns rows tr*8..+7, cols tc4..tc4+3; x from global (broadcast)
    const float* xg = x + (size_t)(b * N_ + r0 + tr * 8) * F_;
    float acc[8][4];
    #pragma unroll
    for (int i = 0; i < 8; ++i)
        #pragma unroll
        for (int j = 0; j < 4; ++j) acc[i][j] = 0.f;

    float4 xa[8], xb[8];
#define LOADX(BUF, K) { _Pragma("unroll") \
    for (int i_ = 0; i_ < 8; ++i_) \
        BUF[i_] = *reinterpret_cast<const float4*>(xg + i_ * F_ + (K)); }
#define FMA4(BUF, KK) { \
    const float4 wv0 = *reinterpret_cast<const float4*>(&wl[((KK) + 0) * 128 + tc4]); \
    const float4 wv1 = *reinterpret_cast<const float4*>(&wl[((KK) + 1) * 128 + tc4]); \
    const float4 wv2 = *reinterpret_cast<const float4*>(&wl[((KK) + 2) * 128 + tc4]); \
    const float4 wv3 = *reinterpret_cast<const float4*>(&wl[((KK) + 3) * 128 + tc4]); \
    _Pragma("unroll") \
    for (int i_ = 0; i_ < 8; ++i_) { \
        acc[i_][0] = fmaf(BUF[i_].x, wv0.x, acc[i_][0]); \
        acc[i_][1] = fmaf(BUF[i_].x, wv0.y, acc[i_][1]); \
        acc[i_][2] = fmaf(BUF[i_].x, wv0.z, acc[i_][2]); \
        acc[i_][3] = fmaf(BUF[i_].x, wv0.w, acc[i_][3]); \
        acc[i_][0] = fmaf(BUF[i_].y, wv1.x, acc[i_][0]); \
        acc[i_][1] = fmaf(BUF[i_].y, wv1.y, acc[i_][1]); \
        acc[i_][2] = fmaf(BUF[i_].y, wv1.z, acc[i_][2]); \
        acc[i_][3] = fmaf(BUF[i_].y, wv1.w, acc[i_][3]); \
        acc[i_][0] = fmaf(BUF[i_].z, wv2.x, acc[i_][0]); \
        acc[i_][1] = fmaf(BUF[i_].z, wv2.y, acc[i_][1]); \
        acc[i_][2] = fmaf(BUF[i_].z, wv2.z, acc[i_][2]); \
        acc[i_][3] = fmaf(BUF[i_].z, wv2.w, acc[i_][3]); \
        acc[i_][0] = fmaf(BUF[i_].w, wv3.x, acc[i_][0]); \
        acc[i_][1] = fmaf(BUF[i_].w, wv3.y, acc[i_][1]); \
        acc[i_][2] = fmaf(BUF[i_].w, wv3.z, acc[i_][2]); \
        acc[i_][3] = fmaf(BUF[i_].w, wv3.w, acc[i_][3]); \
    } }

    LOADX(xa, 0)
    for (int kk = 0; kk < 128; kk += 8) {
        LOADX(xb, kk + 4)
        FMA4(xa, kk)
        if (kk < 120) LOADX(xa, kk + 8)
        FMA4(xb, kk + 4)
    }

    // s0/s1 = t0/t1 @ W (waves 0-1 do s0, waves 2-3 do s1)
    {
        const int c = t & 127;
        const float* tv = (t < 128) ? t0l : t1l;
        float sacc = 0.f;
        #pragma unroll 4
        for (int k = 0; k < 128; ++k)
            sacc = fmaf(tv[k], wl[k * 128 + c], sacc);
        if (t < 128) s0l[c] = sacc; else s1l[c] = sacc;
    }
    __syncthreads();

    // epilogue on register accumulators
    const float4 sb0 = *reinterpret_cast<const float4*>(&s0l[tc4]);
    const float4 sb1 = *reinterpret_cast<const float4*>(&s1l[tc4]);
    const float4 bb  = *reinterpret_cast<const float4*>(&bl[tc4]);
    #pragma unroll
    for (int i = 0; i < 8; ++i) {
        const int row = tr * 8 + i;
        const float d = disl[row], ab = aibl[row];
        float4 o;
        o.x = fmaxf(d * (ab * sb0.x + sb1.x + d * acc[i][0]) + bb.x, 0.f);
        o.y = fmaxf(d * (ab * sb0.y + sb1.y + d * acc[i][1]) + bb.y, 0.f);
        o.z = fmaxf(d * (ab * sb0.z + sb1.z + d * acc[i][2]) + bb.z, 0.f);
        o.w = fmaxf(d * (ab * sb0.w + sb1.w + d * acc[i][3]) + bb.w, 0.f);
        *reinterpret_cast<float4*>(&outx[(size_t)(b * N_ + r0 + row) * F_ + tc4]) = o;
    }
}

extern "C" void kernel_launch(void* const* d_in, const int* in_sizes, int n_in,
                              void* d_out, int out_size, void* d_ws, size_t ws_size,
                              hipStream_t stream) {
    const float* x      = (const float*)d_in[0];
    const float* adj_w  = (const float*)d_in[1];
    const float* adj_b  = (const float*)d_in[2];
    const float* weight = (const float*)d_in[3];
    const float* bias   = (const float*)d_in[4];
    float* out = (float*)d_out;
    float* ws  = (float*)d_ws;

    float* pAj = ws + WS_PAJ;
    float* aib = ws + WS_AIB;
    float* aJ  = ws + WS_AJ;
    float* dis = ws + WS_DIS;
    float* pT0 = ws + WS_PT0;
    float* pT1 = ws + WS_PT1;

    k1_arow<<<512, 256, 0, stream>>>(x, adj_w, adj_b, aib, aJ, pAj);
    k2_tvec<<<512, 256, 0, stream>>>(x, pAj, aib, aJ, dis, pT0, pT1);
    k3_gemm<<<256, 256, 0, stream>>>(x, weight, bias, dis, aib, pT0, pT1, out);
}

// Round 4
// 25.516 us; speedup vs baseline: 4.5761x; 1.0950x over previous
//
#include <hip/hip_runtime.h>

#define N_ 2048
#define F_ 128

// workspace layout (floats)
#define WS_PAJ  0        // [512] per-block partial sums of a_j
#define WS_AIB  512      // [8*2048] a_i + adj_b
#define WS_AJ   16896    // [8*2048] a_j
#define WS_DIS  33280    // [8*2048] dis
#define WS_PT0T 49664    // [8][128][64] partial t0, transposed (col-major over blocks)
#define WS_PT1T 115200   // [8][128][64] partial t1

typedef __attribute__((ext_vector_type(8))) short short8v;
typedef __attribute__((ext_vector_type(4))) float f32x4;

__device__ inline short f2bf(float f) {
    union { float f; unsigned u; } c; c.f = f;
    unsigned r = (c.u + 0x7FFFu + ((c.u >> 16) & 1u)) >> 16;
    return (short)r;
}
__device__ inline float bf2f(short h) {
    union { unsigned u; float f; } c;
    c.u = ((unsigned)(unsigned short)h) << 16;
    return c.f;
}

// ---- K1: per-row a_i,a_j + per-block partial sum(a_j). grid 512 x 256 ----
__global__ __launch_bounds__(256) void k1_arow(
    const float* __restrict__ x, const float* __restrict__ adj_w,
    const float* __restrict__ adj_b_p,
    float* __restrict__ aib, float* __restrict__ aJ, float* __restrict__ pAj)
{
    __shared__ float awl[256];
    __shared__ float sjl[32];
    const int bid = blockIdx.x;
    const int b = bid >> 6, r0 = (bid & 63) * 32;
    const int t = threadIdx.x;
    awl[t] = adj_w[t];
    __syncthreads();
    const int row = t >> 3, kseg = t & 7;
    const float* xp = x + (size_t)(b * N_ + r0 + row) * F_ + kseg * 16;
    float ai = 0.f, aj = 0.f;
    #pragma unroll
    for (int p = 0; p < 4; ++p) {
        const float4 v = *reinterpret_cast<const float4*>(xp + p * 4);
        const float vv[4] = {v.x, v.y, v.z, v.w};
        #pragma unroll
        for (int q = 0; q < 4; ++q) {
            const int k = kseg * 16 + p * 4 + q;
            ai = fmaf(vv[q], awl[k], ai);
            aj = fmaf(vv[q], awl[128 + k], aj);
        }
    }
    #pragma unroll
    for (int m = 1; m < 8; m <<= 1) {
        ai += __shfl_xor(ai, m, 64);
        aj += __shfl_xor(aj, m, 64);
    }
    if (kseg == 0) {
        aib[b * N_ + r0 + row] = ai + adj_b_p[0];
        aJ[b * N_ + r0 + row] = aj;
        sjl[row] = aj;
    }
    __syncthreads();
    if (t < 32) {
        float s = sjl[t];
        #pragma unroll
        for (int off = 16; off > 0; off >>= 1) s += __shfl_down(s, off, 32);
        if (t == 0) pAj[bid] = s;
    }
}

// ---- K2: dis per row + per-block partial t0/t1 (transposed out). grid 512 x 256 ----
__global__ __launch_bounds__(256) void k2_tvec(
    const float* __restrict__ x, const float* __restrict__ pAj,
    const float* __restrict__ aib, const float* __restrict__ aJ,
    float* __restrict__ dis, float* __restrict__ pT0T, float* __restrict__ pT1T)
{
    __shared__ float al[64];
    __shared__ float disl[32], ajdl[32];
    __shared__ float red[2][128];
    const int bid = blockIdx.x;
    const int b = bid >> 6, r0 = (bid & 63) * 32;
    const int t = threadIdx.x;
    if (t < 64) al[t] = pAj[b * 64 + t];
    __syncthreads();
    if (t < 32) {
        float A = 0.f;
        #pragma unroll
        for (int i = 0; i < 64; ++i) A += al[i];
        const float ab = aib[b * N_ + r0 + t];
        const float deg = fmaxf(2048.f * ab + A + 1.f, 1.f);
        const float d = rsqrtf(deg);
        dis[b * N_ + r0 + t] = d;
        disl[t] = d;
        ajdl[t] = aJ[b * N_ + r0 + t] * d;
    }
    __syncthreads();
    const int c = t & 127, g = t >> 7;
    float s0 = 0.f, s1 = 0.f;
    const float* xp = x + (size_t)(b * N_ + r0 + g * 16) * F_;
    #pragma unroll 4
    for (int r = 0; r < 16; ++r) {
        const float v = xp[r * F_ + c];
        s0 = fmaf(disl[g * 16 + r], v, s0);
        s1 = fmaf(ajdl[g * 16 + r], v, s1);
    }
    red[g][c] = s0;
    __syncthreads();
    if (t < 128) pT0T[(size_t)(b * 128 + t) * 64 + (bid & 63)] = red[0][t] + red[1][t];
    __syncthreads();
    red[g][c] = s1;
    __syncthreads();
    if (t < 128) pT1T[(size_t)(b * 128 + t) * 64 + (bid & 63)] = red[0][t] + red[1][t];
}

// ---- K3: bf16-MFMA GEMM + s0/s1 + epilogue, single out write. grid 512 x 256 ----
__global__ __launch_bounds__(256) void k3_gemm(
    const float* __restrict__ x, const float* __restrict__ weight,
    const float* __restrict__ bias, const float* __restrict__ dis,
    const float* __restrict__ aib, const float* __restrict__ pT0T,
    const float* __restrict__ pT1T, float* __restrict__ outx)
{
    // WT: W transposed to bf16, [col][k], 16B slots XOR-swizzled: slot = kb ^ (col&15)
    __shared__ unsigned short wt[128 * 128];
    __shared__ float t0l[128], t1l[128], s0l[128], s1l[128], bl[128];
    __shared__ float disl[32], aibl[32];

    const int bid = blockIdx.x;
    const int b = bid >> 6, r0 = (bid & 63) * 32;
    const int t = threadIdx.x;
    const int lane = t & 63, w = t >> 6;
    const int u = lane & 15, g = lane >> 4;

    // ---- stage W^T bf16 (reads: 256B-coalesced per instr; writes: 2-way/phase)
    {
        const int c = t & 127, khalf = t >> 7;
        for (int j8 = 0; j8 < 8; ++j8) {
            const int kb = khalf * 8 + j8;
            short8v v;
            #pragma unroll
            for (int i = 0; i < 8; ++i)
                v[i] = f2bf(weight[(kb * 8 + i) * F_ + c]);
            const int slot = kb ^ (c & 15);
            *reinterpret_cast<short8v*>(&wt[c * 128 + slot * 8]) = v;
        }
    }
    // ---- reduce t0/t1 partials (contiguous float4 per thread)
    if (t < 128) {
        const float4* p = reinterpret_cast<const float4*>(pT0T + (size_t)(b * 128 + t) * 64);
        float sx = 0.f, sy = 0.f, sz = 0.f, sw = 0.f;
        #pragma unroll
        for (int i = 0; i < 16; ++i) {
            const float4 v = p[i];
            sx += v.x; sy += v.y; sz += v.z; sw += v.w;
        }
        t0l[t] = (sx + sy) + (sz + sw);
        bl[t] = bias[t];
    } else {
        const int c = t - 128;
        const float4* p = reinterpret_cast<const float4*>(pT1T + (size_t)(b * 128 + c) * 64);
        float sx = 0.f, sy = 0.f, sz = 0.f, sw = 0.f;
        #pragma unroll
        for (int i = 0; i < 16; ++i) {
            const float4 v = p[i];
            sx += v.x; sy += v.y; sz += v.z; sw += v.w;
        }
        t1l[c] = (sx + sy) + (sz + sw);
    }
    if (t < 32) {
        disl[t] = dis[b * N_ + r0 + t];
        aibl[t] = aib[b * N_ + r0 + t];
    }
    __syncthreads();

    // ---- MFMA GEMM: wave w -> rows (w&1)*16.., col-tiles (w>>1)*4..
    const int wr = (w & 1) * 16;
    const int ct0 = (w >> 1) * 4;
    f32x4 acc[4];
    #pragma unroll
    for (int i = 0; i < 4; ++i) acc[i] = (f32x4)(0.f);

    const float* xrow = x + (size_t)(b * N_ + r0 + wr + u) * F_;
    #pragma unroll
    for (int kk = 0; kk < 4; ++kk) {
        const float4 xa = *reinterpret_cast<const float4*>(xrow + kk * 32 + g * 8);
        const float4 xb = *reinterpret_cast<const float4*>(xrow + kk * 32 + g * 8 + 4);
        short8v af;
        af[0] = f2bf(xa.x); af[1] = f2bf(xa.y); af[2] = f2bf(xa.z); af[3] = f2bf(xa.w);
        af[4] = f2bf(xb.x); af[5] = f2bf(xb.y); af[6] = f2bf(xb.z); af[7] = f2bf(xb.w);
        const int kb = kk * 4 + g;
        #pragma unroll
        for (int c = 0; c < 4; ++c) {
            const int col = (ct0 + c) * 16 + u;
            const int slot = kb ^ u;   // col&15 == u
            const short8v bfv = *reinterpret_cast<const short8v*>(&wt[col * 128 + slot * 8]);
            acc[c] = __builtin_amdgcn_mfma_f32_16x16x32_bf16(af, bfv, acc[c], 0, 0, 0);
        }
    }

    // ---- s0/s1 = t0/t1 @ W (per-thread one (vec,col) pair)
    {
        const int c = t & 127;
        const float* tv = (t < 128) ? t0l : t1l;
        float sacc = 0.f;
        for (int kb = 0; kb < 16; ++kb) {
            const int slot = kb ^ (c & 15);
            const short8v v = *reinterpret_cast<const short8v*>(&wt[c * 128 + slot * 8]);
            #pragma unroll
            for (int i = 0; i < 8; ++i)
                sacc = fmaf(tv[kb * 8 + i], bf2f(v[i]), sacc);
        }
        if (t < 128) s0l[c] = sacc; else s1l[c] = sacc;
    }
    __syncthreads();

    // ---- epilogue on MFMA accumulators: D[row=(l>>4)*4+r][col=l&15] per tile
    #pragma unroll
    for (int c = 0; c < 4; ++c) {
        const int col = (ct0 + c) * 16 + u;
        const float sv0 = s0l[col], sv1 = s1l[col], bv = bl[col];
        #pragma unroll
        for (int r = 0; r < 4; ++r) {
            const int row = wr + g * 4 + r;
            const float d = disl[row], ab = aibl[row];
            const float o = fmaxf(d * (ab * sv0 + sv1 + d * acc[c][r]) + bv, 0.f);
            outx[(size_t)(b * N_ + r0 + row) * F_ + col] = o;
        }
    }
}

extern "C" void kernel_launch(void* const* d_in, const int* in_sizes, int n_in,
                              void* d_out, int out_size, void* d_ws, size_t ws_size,
                              hipStream_t stream) {
    const float* x      = (const float*)d_in[0];
    const float* adj_w  = (const float*)d_in[1];
    const float* adj_b  = (const float*)d_in[2];
    const float* weight = (const float*)d_in[3];
    const float* bias   = (const float*)d_in[4];
    float* out = (float*)d_out;
    float* ws  = (float*)d_ws;

    float* pAj  = ws + WS_PAJ;
    float* aib  = ws + WS_AIB;
    float* aJ   = ws + WS_AJ;
    float* dis  = ws + WS_DIS;
    float* pT0T = ws + WS_PT0T;
    float* pT1T = ws + WS_PT1T;

    k1_arow<<<512, 256, 0, stream>>>(x, adj_w, adj_b, aib, aJ, pAj);
    k2_tvec<<<512, 256, 0, stream>>>(x, pAj, aib, aJ, dis, pT0T, pT1T);
    k3_gemm<<<512, 256, 0, stream>>>(x, weight, bias, dis, aib, pT0T, pT1T, out);
}

// Round 5
// 20.932 us; speedup vs baseline: 5.5782x; 1.2190x over previous
//
#include <hip/hip_runtime.h>

#define N_ 2048
#define F_ 128

// workspace (u64 units): P1[512] tagged a_j partials; P2[8*64*128] records of
// 2 u64 each: {t0,tag},{t1,tag}
#define WS_P1 0
#define WS_P2 512

typedef __attribute__((ext_vector_type(8))) short short8v;
typedef __attribute__((ext_vector_type(4))) float f32x4;
typedef unsigned long long u64;

__device__ inline short f2bf(float f) {
    union { float f; unsigned u; } c; c.f = f;
    unsigned r = (c.u + 0x7FFFu + ((c.u >> 16) & 1u)) >> 16;
    return (short)r;
}
__device__ inline float bf2f(short h) {
    union { unsigned u; float f; } c;
    c.u = ((unsigned)(unsigned short)h) << 16;
    return c.f;
}
__device__ inline void store_pair(u64* p, float f) {
    union { float f; unsigned u; } c; c.f = f;
    const u64 v = ((u64)(~c.u) << 32) | (u64)c.u;
    __hip_atomic_store(p, v, __ATOMIC_RELAXED, __HIP_MEMORY_SCOPE_AGENT);
}
__device__ inline bool pair_ok(u64 v) {
    return (unsigned)(v >> 32) == (unsigned)(~(unsigned)v);
}
__device__ inline float pair_val(u64 v) {
    union { unsigned u; float f; } c; c.u = (unsigned)v;
    return c.f;
}

__global__ __launch_bounds__(256, 2) void gcn_one(
    const float* __restrict__ x, const float* __restrict__ adj_w,
    const float* __restrict__ adj_b_p, const float* __restrict__ weight,
    const float* __restrict__ bias, float* __restrict__ outx,
    u64* __restrict__ P1, u64* __restrict__ P2)
{
    __shared__ unsigned short wt[128 * 128];   // W^T bf16, slot-swizzled
    __shared__ float adjw[256];
    __shared__ float ail[32], ajl[32];         // a_i + adj_b, a_j
    __shared__ float disl[32], ajdl[32];
    __shared__ float red0[2][128], red1[2][128];
    __shared__ float t0l[128], t1l[128], s0l[128], s1l[128], bl[128];
    __shared__ float Ash;

    const int bid = blockIdx.x;
    const int b = bid >> 6, kbme = bid & 63, r0 = kbme * 32;
    const int t = threadIdx.x;
    const int lane = t & 63, w = t >> 6;
    const int u = lane & 15, g = lane >> 4;

    adjw[t] = adj_w[t];
    if (t < 128) bl[t] = bias[t];
    __syncthreads();

    // ---- phase 1: per-row a_i, a_j (coalesced x read; this is x's HBM fetch)
    {
        const int row = t >> 3, kseg = t & 7;
        const float* xp = x + (size_t)(b * N_ + r0 + row) * F_ + kseg * 16;
        float ai = 0.f, aj = 0.f;
        #pragma unroll
        for (int p = 0; p < 4; ++p) {
            const float4 v = *reinterpret_cast<const float4*>(xp + p * 4);
            const float vv[4] = {v.x, v.y, v.z, v.w};
            #pragma unroll
            for (int q = 0; q < 4; ++q) {
                const int k = kseg * 16 + p * 4 + q;
                ai = fmaf(vv[q], adjw[k], ai);
                aj = fmaf(vv[q], adjw[128 + k], aj);
            }
        }
        #pragma unroll
        for (int m = 1; m < 8; m <<= 1) {
            ai += __shfl_xor(ai, m, 64);
            aj += __shfl_xor(aj, m, 64);
        }
        if (kseg == 0) { ail[row] = ai + adj_b_p[0]; ajl[row] = aj; }
    }
    __syncthreads();
    // block partial sum of a_j -> P1 (tagged)
    if (t < 32) {
        float s = ajl[t];
        #pragma unroll
        for (int off = 16; off > 0; off >>= 1) s += __shfl_down(s, off, 64);
        if (t == 0) store_pair(&P1[bid], s);
    }

    // ---- stage W^T bf16 (independent of barriers; hides P1 propagation)
    {
        const int c = t & 127, khalf = t >> 7;
        for (int j8 = 0; j8 < 8; ++j8) {
            const int kb = khalf * 8 + j8;
            short8v v;
            #pragma unroll
            for (int i = 0; i < 8; ++i)
                v[i] = f2bf(weight[(kb * 8 + i) * F_ + c]);
            const int slot = kb ^ (c & 15);
            *reinterpret_cast<short8v*>(&wt[c * 128 + slot * 8]) = v;
        }
    }
    __syncthreads();

    // ---- MFMA GEMM (independent of both barriers -> overlaps barrier-A skew)
    const int wr = (w & 1) * 16;
    const int ct0 = (w >> 1) * 4;
    f32x4 acc[4];
    #pragma unroll
    for (int i = 0; i < 4; ++i) acc[i] = (f32x4)(0.f);
    {
        const float* xrow = x + (size_t)(b * N_ + r0 + wr + u) * F_;
        #pragma unroll
        for (int kk = 0; kk < 4; ++kk) {
            const float4 xa = *reinterpret_cast<const float4*>(xrow + kk * 32 + g * 8);
            const float4 xb = *reinterpret_cast<const float4*>(xrow + kk * 32 + g * 8 + 4);
            short8v af;
            af[0] = f2bf(xa.x); af[1] = f2bf(xa.y); af[2] = f2bf(xa.z); af[3] = f2bf(xa.w);
            af[4] = f2bf(xb.x); af[5] = f2bf(xb.y); af[6] = f2bf(xb.z); af[7] = f2bf(xb.w);
            const int kb = kk * 4 + g;
            #pragma unroll
            for (int c = 0; c < 4; ++c) {
                const int col = (ct0 + c) * 16 + u;
                const int slot = kb ^ u;   // col&15 == u
                const short8v bfv = *reinterpret_cast<const short8v*>(&wt[col * 128 + slot * 8]);
                acc[c] = __builtin_amdgcn_mfma_f32_16x16x32_bf16(af, bfv, acc[c], 0, 0, 0);
            }
        }
    }

    // ---- barrier A: spin on the 64 tagged P1 partials of this batch
    if (t < 64) {
        u64 v;
        do {
            v = __hip_atomic_load(&P1[b * 64 + t], __ATOMIC_RELAXED, __HIP_MEMORY_SCOPE_AGENT);
        } while (!pair_ok(v));
        float s = pair_val(v);
        #pragma unroll
        for (int off = 32; off > 0; off >>= 1) s += __shfl_down(s, off, 64);
        if (t == 0) Ash = s;
    }
    __syncthreads();
    if (t < 32) {
        const float deg = fmaxf(2048.f * ail[t] + Ash + 1.f, 1.f);
        const float d = rsqrtf(deg);
        disl[t] = d;
        ajdl[t] = ajl[t] * d;
    }
    __syncthreads();

    // ---- t0/t1 partials over this block's 32 rows (x re-read is L1/L2-hot)
    {
        const int c = t & 127, gh = t >> 7;
        float s0 = 0.f, s1 = 0.f;
        const float* xp = x + (size_t)(b * N_ + r0 + gh * 16) * F_;
        #pragma unroll 4
        for (int r = 0; r < 16; ++r) {
            const float v = xp[r * F_ + c];
            s0 = fmaf(disl[gh * 16 + r], v, s0);
            s1 = fmaf(ajdl[gh * 16 + r], v, s1);
        }
        red0[gh][c] = s0;
        red1[gh][c] = s1;
    }
    __syncthreads();
    if (t < 128) {
        const size_t rec = ((size_t)(b * 64 + kbme) * 128 + t) * 2;
        store_pair(&P2[rec], red0[0][t] + red0[1][t]);
        store_pair(&P2[rec + 1], red1[0][t] + red1[1][t]);
    }
    __syncthreads();   // red0/red1 reusable below

    // ---- barrier B + reduce: each thread sums 32 kb-slots for its column
    {
        const int c = t & 127, kh = t >> 7;   // kh: kb 0..31 or 32..63
        float s0 = 0.f, s1 = 0.f;
        #pragma unroll 1
        for (int kb0 = 0; kb0 < 32; kb0 += 8) {
            u64 v0[8], v1[8];
            bool ok;
            do {
                ok = true;
                #pragma unroll
                for (int i = 0; i < 8; ++i) {
                    const size_t rec = ((size_t)(b * 64 + kh * 32 + kb0 + i) * 128 + c) * 2;
                    v0[i] = __hip_atomic_load(&P2[rec], __ATOMIC_RELAXED, __HIP_MEMORY_SCOPE_AGENT);
                    v1[i] = __hip_atomic_load(&P2[rec + 1], __ATOMIC_RELAXED, __HIP_MEMORY_SCOPE_AGENT);
                }
                #pragma unroll
                for (int i = 0; i < 8; ++i) ok &= pair_ok(v0[i]) & pair_ok(v1[i]);
                if (!ok) __builtin_amdgcn_s_sleep(1);
            } while (!ok);
            #pragma unroll
            for (int i = 0; i < 8; ++i) { s0 += pair_val(v0[i]); s1 += pair_val(v1[i]); }
        }
        red0[kh][c] = s0;
        red1[kh][c] = s1;
    }
    __syncthreads();
    if (t < 128) t0l[t] = red0[0][t] + red0[1][t];
    else { const int c = t - 128; t1l[c] = red1[0][c] + red1[1][c]; }
    __syncthreads();

    // ---- s0/s1 = t0/t1 @ W (bf16 W from LDS)
    {
        const int c = t & 127;
        const float* tv = (t < 128) ? t0l : t1l;
        float sacc = 0.f;
        for (int kb = 0; kb < 16; ++kb) {
            const int slot = kb ^ (c & 15);
            const short8v v = *reinterpret_cast<const short8v*>(&wt[c * 128 + slot * 8]);
            #pragma unroll
            for (int i = 0; i < 8; ++i)
                sacc = fmaf(tv[kb * 8 + i], bf2f(v[i]), sacc);
        }
        if (t < 128) s0l[c] = sacc; else s1l[c] = sacc;
    }
    __syncthreads();

    // ---- epilogue on MFMA accumulators, single out write
    #pragma unroll
    for (int c = 0; c < 4; ++c) {
        const int col = (ct0 + c) * 16 + u;
        const float sv0 = s0l[col], sv1 = s1l[col], bv = bl[col];
        #pragma unroll
        for (int r = 0; r < 4; ++r) {
            const int row = wr + g * 4 + r;
            const float d = disl[row], ab = ail[row];
            const float o = fmaxf(d * (ab * sv0 + sv1 + d * acc[c][r]) + bv, 0.f);
            outx[(size_t)(b * N_ + r0 + row) * F_ + col] = o;
        }
    }
}

extern "C" void kernel_launch(void* const* d_in, const int* in_sizes, int n_in,
                              void* d_out, int out_size, void* d_ws, size_t ws_size,
                              hipStream_t stream) {
    const float* x      = (const float*)d_in[0];
    const float* adj_w  = (const float*)d_in[1];
    const float* adj_b  = (const float*)d_in[2];
    const float* weight = (const float*)d_in[3];
    const float* bias   = (const float*)d_in[4];
    float* out = (float*)d_out;
    u64* ws = (u64*)d_ws;

    gcn_one<<<512, 256, 0, stream>>>(x, adj_w, adj_b, weight, bias, out,
                                     ws + WS_P1, ws + WS_P2);
}